// Round 17
// baseline (336.189 us; speedup 1.0000x reference)
//
#include <hip/hip_runtime.h>
#include <hip/hip_fp16.h>
#include <cstdint>
#include <cstddef>

#define Nn 50000
#define Ne 800000
#define Ng 1024
#define NFd 32
#define Rr 4
#define Hd 64
#define Od 16
#define MAXD 10
#define NBKT 64                            // buckets = unclamped degree (clamp 63)
#define NSEG (Nn * Rr)
#define SCAN_BLK ((NSEG + 255) / 256)
#define ORDER_SZ (Nn + 960)                // 64 buckets x up-to-15 pad; 50960/16 exact
#define NB_MF (ORDER_SZ / 16)              // block = 16 slots (length-uniform), 4 waves
#define NB_RG (Nn / 16)                    // block = 4 waves; 16 nodes/block (MFMA tile)
#define NB_RELSEG (Ne / 256)               // 3125 edge blocks
#define NB_EMBED (Nn / 8)                  // 6250 embed blocks (2 nodes/wave)
#define WT_PER_LAYER (Hd * 5 * Hd)         // 20480 halves: [64 cols][320 k]
#define MFWT_PER_LAYER ((MAXD + 1) * Hd * 2 * Hd)  // 90112 halves: [d][64 cols][128 k]
#define PREP_TOTAL (2 * WT_PER_LAYER + 2 * MFWT_PER_LAYER)
#define NB_PREP ((PREP_TOTAL + 255) / 256) // 864 blocks, folded into k_rel_emb grid

typedef _Float16 f16x8 __attribute__((ext_vector_type(8)));
typedef float f32x4 __attribute__((ext_vector_type(4)));

__device__ __forceinline__ float reluf(float v) { return v > 0.f ? v : 0.f; }
__device__ __forceinline__ int rfl(int v) { return __builtin_amdgcn_readfirstlane(v); }

// ---- FUSED: per-edge relation argmax/rank + embedding lookup + weight prep ----
// seg+rank packed into ONE int: (s << 12) | rank.
__global__ void k_rel_emb(const float4* __restrict__ ea, const int* __restrict__ eidx,
                          int* __restrict__ segrank,
                          int* __restrict__ cnt,
                          const float* __restrict__ x, const float* __restrict__ emb,
                          __half* __restrict__ h16,
                          const float* __restrict__ w0, const float* __restrict__ r0,
                          const float* __restrict__ w1, const float* __restrict__ r1,
                          const float* __restrict__ wl0, const float* __restrict__ wr0,
                          const float* __restrict__ wl1, const float* __restrict__ wr1,
                          __half* __restrict__ wt, __half* __restrict__ mfwt) {
    if (blockIdx.x < NB_RELSEG) {
        int e = blockIdx.x * 256 + threadIdx.x;     // exactly e < Ne
        float4 a = ea[e];
        int bi = 0; float bv = a.x;
        if (a.y > bv) { bv = a.y; bi = 1; }
        if (a.z > bv) { bv = a.z; bi = 2; }
        if (a.w > bv) { bv = a.w; bi = 3; }
        int s = eidx[Ne + e] * Rr + bi;
        int rk = atomicAdd(&cnt[s], 1);
        segrank[e] = (s << 12) | rk;
    } else if (blockIdx.x < NB_RELSEG + NB_EMBED) {
        int wave = ((blockIdx.x - NB_RELSEG) * 256 + threadIdx.x) >> 6;  // < Nn/2
        int lane = threadIdx.x & 63;
        int h = lane >> 5, q = lane & 31;
        int node = wave * 2 + h;
        float v = x[(size_t)node * NFd + q];
        int idx = q;
        #pragma unroll
        for (int o = 16; o >= 1; o >>= 1) {         // xor-butterfly within half-wave
            float ov = __shfl_xor(v, o);
            int oi = __shfl_xor(idx, o);
            if (ov > v || (ov == v && oi < idx)) { v = ov; idx = oi; }
        }
        const float2* e2 = (const float2*)(emb + (size_t)idx * Hd);
        float2 ev = e2[q];
        ((__half2*)h16)[(size_t)node * 32 + q] =
            __floats2half2_rn(reluf(ev.x), reluf(ev.y));
    } else {
        // weight prep:
        // wt  [layer][c][320]:  k<64 -> Wroot[k][c]; k=64+64r+kk -> W[r][kk][c]
        // mfwt[layer][d][c][128]: k<64 -> Wl[d][k][c]; k>=64 -> Wr[d][k-64][c]
        int idx = (blockIdx.x - NB_RELSEG - NB_EMBED) * 256 + threadIdx.x;
        if (idx < 2 * WT_PER_LAYER) {
            int b = idx / WT_PER_LAYER;
            int rem = idx % WT_PER_LAYER;
            int c = rem / 320;
            int k = rem % 320;
            const float* W  = b ? w1 : w0;
            const float* Rt = b ? r1 : r0;
            float v = (k < 64) ? Rt[k * Hd + c]
                               : W[((size_t)((k - 64) >> 6)) * Hd * Hd + ((k - 64) & 63) * Hd + c];
            wt[idx] = __float2half(v);
        } else if (idx < PREP_TOTAL) {
            int j = idx - 2 * WT_PER_LAYER;
            int b = j / MFWT_PER_LAYER;
            int rem = j % MFWT_PER_LAYER;
            int d = rem / (Hd * 128);
            int r2 = rem % (Hd * 128);
            int c = r2 / 128;
            int k = r2 % 128;
            const float* Wl = b ? wl1 : wl0;
            const float* Wr = b ? wr1 : wr0;
            float v = (k < 64) ? Wl[(size_t)d * Hd * Hd + k * Hd + c]
                               : Wr[(size_t)d * Hd * Hd + (k - 64) * Hd + c];
            mfwt[j] = __float2half(v);
        }
    }
}

// ---- scan level 1 + fused degree histogram (UNCLAMPED degree key, 64 buckets) ----
__global__ void k_scan1(const int* __restrict__ cnt, int* __restrict__ off,
                        int* __restrict__ bsum, int* __restrict__ bcnt) {
    __shared__ int s[256];
    __shared__ int hist[NBKT];
    int t = threadIdx.x;
    if (t < NBKT) hist[t] = 0;
    int idx = blockIdx.x * 256 + t;
    int v = (idx < NSEG) ? cnt[idx] : 0;
    s[t] = v;
    __syncthreads();
    if ((t & 3) == 0 && idx < NSEG) {
        int dsum = s[t] + s[t + 1] + s[t + 2] + s[t + 3];
        atomicAdd(&hist[min(dsum, NBKT - 1)], 1);
    }
    #pragma unroll
    for (int o = 1; o < 256; o <<= 1) {
        int x = (t >= o) ? s[t - o] : 0;
        __syncthreads();
        s[t] += x;
        __syncthreads();
    }
    if (idx < NSEG) off[idx] = s[t] - v;            // exclusive
    if (t == 255) bsum[blockIdx.x] = s[255];
    if (t < NBKT) {
        int h = hist[t];
        if (h > 0) atomicAdd(&bcnt[t], h);
    }
}

// ---- scan level 2 + fused bucket prefix (16-aligned, 64 buckets) ----
__global__ void k_scan2(int* __restrict__ bsum, const int* __restrict__ bcnt,
                        int* __restrict__ bbase, int* __restrict__ order) {
    __shared__ int s[1024];
    int t = threadIdx.x;
    int v = (t < SCAN_BLK) ? bsum[t] : 0;
    s[t] = v;
    __syncthreads();
    #pragma unroll
    for (int o = 1; o < 1024; o <<= 1) {
        int x = (t >= o) ? s[t - o] : 0;
        __syncthreads();
        s[t] += x;
        __syncthreads();
    }
    if (t < SCAN_BLK) bsum[t] = s[t] - v;           // exclusive block bases
    if (t == 0) {
        int run = 0;
        for (int d = 0; d < NBKT; d++) {
            int c = bcnt[d];
            bbase[d] = run;
            int pad = (c + 15) & ~15;               // x16: MFMA tile = length-uniform
            for (int i = c; i < pad; i++) order[run + i] = -1;
            run += pad;
        }
        for (int i = run; i < ORDER_SZ; i++) order[i] = -1;
    }
}

// ---- FUSED: scan level 3 (final off)  +  degree-bucket scatter (64 buckets) ----
__global__ void k_scan3_bucket(int* __restrict__ off, const int* __restrict__ bsum,
                               const int4* __restrict__ cnt4, const int* __restrict__ bbase,
                               int* __restrict__ bfill, int* __restrict__ order) {
    __shared__ int hist[NBKT];
    __shared__ int base[NBKT];
    int t = threadIdx.x;
    if (t < NBKT) hist[t] = 0;
    __syncthreads();
    int idx = blockIdx.x * 256 + t;
    if (idx == 0) off[NSEG] = Ne;
    if (idx < NSEG) off[idx] = off[idx] + bsum[blockIdx.x];
    int d = 0, rk = 0;
    bool valid = (idx < Nn);
    if (valid) {
        int4 c = cnt4[idx];
        d = min(c.x + c.y + c.z + c.w, NBKT - 1);
        rk = atomicAdd(&hist[d], 1);
    }
    __syncthreads();
    if (t < NBKT) {
        int h = hist[t];
        base[t] = (h > 0) ? atomicAdd(&bfill[t], h) : 0;
    }
    __syncthreads();
    if (valid) order[bbase[d] + base[d] + rk] = idx | (d << 20);
}

// ---- scatter edges into segment-sorted order: NO atomics (packed seg+rank) ----
__global__ void k_scatter(const int* __restrict__ eidx, const int* __restrict__ segrank,
                          const int* __restrict__ off, int* __restrict__ sorted_src) {
    int e = blockIdx.x * 256 + threadIdx.x;
    if (e >= Ne) return;
    int sr = segrank[e];
    int pos = off[sr >> 12] + (sr & 0xFFF);
    sorted_src[pos] = eidx[e];
}

// ---- FUSED RGCN layer: paired-edge fp16 gather, 32-edge chunks -> MFMA ----
// Half-wave h processes edge t+h of each pair; lane q=lane&31 holds cols {2q,2q+1}.
// 16 row-loads + 8 prefetched idx-loads in flight per chunk (straight-line body).
__global__ __launch_bounds__(256) void k_rgcn_fused(
        const __half* __restrict__ hin16,
        const int* __restrict__ off, const int* __restrict__ ssrc,
        const __half* __restrict__ wt, const float* __restrict__ bias,
        __half* __restrict__ hout16) {
    __shared__ __align__(16) __half alds[16 * 296];  // [node]: rel*72 + k; node stride 296
    int tid = threadIdx.x;
    int wv = tid >> 6, lane = tid & 63;
    int h = lane >> 5, q = lane & 31;
    int nblk = rfl(blockIdx.x * 16);
    int n0 = nblk + wv * 4;
    int obv = off[4 * n0 + min(lane, 16)];          // boundaries live in lanes
    int cntv = __shfl(obv, lane + 1) - obv;
    float ivv = (cntv > 0) ? 1.f / (float)cntv : 0.f;
    int e    = rfl(__shfl(obv, 0));
    int eEnd = rfl(__shfl(obv, 16));
    const __half2* hp = (const __half2*)hin16;      // row = 32 half2

    float ax = 0.f, ay = 0.f;                       // running prefix (per half)
    float px = 0.f, py = 0.f;                       // snapshot
    float vx = 0.f, vy = 0.f;                       // half's most recent added value
    int segi = 0;
    int nb = rfl(__shfl(obv, 1));

#define EMIT(SUB) do {                                               \
        float dx = ax - px, dy = ay - py;                            \
        float ox = ((SUB) && h) ? vx : 0.f;                          \
        float oy = ((SUB) && h) ? vy : 0.f;                          \
        dx -= ox; dy -= oy;                                          \
        dx += __shfl_xor(dx, 32); dy += __shfl_xor(dy, 32);          \
        float iv_ = __shfl(ivv, segi);                               \
        if (lane < 32)                                               \
            *(__half2*)&alds[(wv * 4 + (segi >> 2)) * 296            \
                             + (segi & 3) * 72 + 2 * q]              \
                = __floats2half2_rn(dx * iv_, dy * iv_);             \
        px = ax - ox; py = ay - oy;                                  \
        segi++;                                                      \
        nb = (segi < 16) ? rfl(__shfl(obv, segi + 1)) : 0x7fffffff;  \
    } while (0)

#define PSTEP(dj, t0) {                                              \
        while ((t0) == nb) EMIT(0);                                  \
        float2 f_ = __half22float2(dj);                              \
        vx = f_.x; vy = f_.y; ax += f_.x; ay += f_.y;                \
        while ((t0) + 1 == nb) EMIT(1); }

    if (e + 32 <= eEnd) {                           // 32-edge chunks, deep pipeline
        int4 iA = *(const int4*)(ssrc + e);
        int4 iB = *(const int4*)(ssrc + e + 4);
        int4 iC = *(const int4*)(ssrc + e + 8);
        int4 iD = *(const int4*)(ssrc + e + 12);
        int4 iE = *(const int4*)(ssrc + e + 16);
        int4 iF = *(const int4*)(ssrc + e + 20);
        int4 iG = *(const int4*)(ssrc + e + 24);
        int4 iH = *(const int4*)(ssrc + e + 28);
        while (true) {
            int s0 = h ? iA.y : iA.x;               // pair j: edges e+2j, e+2j+1
            int s1 = h ? iA.w : iA.z;
            int s2 = h ? iB.y : iB.x;
            int s3 = h ? iB.w : iB.z;
            int s4 = h ? iC.y : iC.x;
            int s5 = h ? iC.w : iC.z;
            int s6 = h ? iD.y : iD.x;
            int s7 = h ? iD.w : iD.z;
            int s8 = h ? iE.y : iE.x;
            int s9 = h ? iE.w : iE.z;
            int sA = h ? iF.y : iF.x;
            int sB = h ? iF.w : iF.z;
            int sC = h ? iG.y : iG.x;
            int sD = h ? iG.w : iG.z;
            int sE = h ? iH.y : iH.x;
            int sF = h ? iH.w : iH.z;
            __half2 d0 = hp[s0 * 32 + q];           // 16 paired loads in flight
            __half2 d1 = hp[s1 * 32 + q];
            __half2 d2 = hp[s2 * 32 + q];
            __half2 d3 = hp[s3 * 32 + q];
            __half2 d4 = hp[s4 * 32 + q];
            __half2 d5 = hp[s5 * 32 + q];
            __half2 d6 = hp[s6 * 32 + q];
            __half2 d7 = hp[s7 * 32 + q];
            __half2 d8 = hp[s8 * 32 + q];
            __half2 d9 = hp[s9 * 32 + q];
            __half2 dA = hp[sA * 32 + q];
            __half2 dB = hp[sB * 32 + q];
            __half2 dC = hp[sC * 32 + q];
            __half2 dD = hp[sD * 32 + q];
            __half2 dE = hp[sE * 32 + q];
            __half2 dF = hp[sF * 32 + q];
            int en = e + 32;
            bool more = (en + 32 <= eEnd);
            int4 jA, jB, jC, jD, jE, jF, jG, jH;
            if (more) {                             // prefetch next chunk's indices
                jA = *(const int4*)(ssrc + en);
                jB = *(const int4*)(ssrc + en + 4);
                jC = *(const int4*)(ssrc + en + 8);
                jD = *(const int4*)(ssrc + en + 12);
                jE = *(const int4*)(ssrc + en + 16);
                jF = *(const int4*)(ssrc + en + 20);
                jG = *(const int4*)(ssrc + en + 24);
                jH = *(const int4*)(ssrc + en + 28);
            }
            PSTEP(d0, e + 0)  PSTEP(d1, e + 2)  PSTEP(d2, e + 4)  PSTEP(d3, e + 6)
            PSTEP(d4, e + 8)  PSTEP(d5, e + 10) PSTEP(d6, e + 12) PSTEP(d7, e + 14)
            PSTEP(d8, e + 16) PSTEP(d9, e + 18) PSTEP(dA, e + 20) PSTEP(dB, e + 22)
            PSTEP(dC, e + 24) PSTEP(dD, e + 26) PSTEP(dE, e + 28) PSTEP(dF, e + 30)
            e = en;
            if (!more) break;
            iA = jA; iB = jB; iC = jC; iD = jD;
            iE = jE; iF = jF; iG = jG; iH = jH;
        }
    }
    if (e + 16 <= eEnd) {                           // tail: at most one 16-chunk
        int4 iA = *(const int4*)(ssrc + e);
        int4 iB = *(const int4*)(ssrc + e + 4);
        int4 iC = *(const int4*)(ssrc + e + 8);
        int4 iD = *(const int4*)(ssrc + e + 12);
        int s0 = h ? iA.y : iA.x;
        int s1 = h ? iA.w : iA.z;
        int s2 = h ? iB.y : iB.x;
        int s3 = h ? iB.w : iB.z;
        int s4 = h ? iC.y : iC.x;
        int s5 = h ? iC.w : iC.z;
        int s6 = h ? iD.y : iD.x;
        int s7 = h ? iD.w : iD.z;
        __half2 d0 = hp[s0 * 32 + q];
        __half2 d1 = hp[s1 * 32 + q];
        __half2 d2 = hp[s2 * 32 + q];
        __half2 d3 = hp[s3 * 32 + q];
        __half2 d4 = hp[s4 * 32 + q];
        __half2 d5 = hp[s5 * 32 + q];
        __half2 d6 = hp[s6 * 32 + q];
        __half2 d7 = hp[s7 * 32 + q];
        PSTEP(d0, e + 0)  PSTEP(d1, e + 2)  PSTEP(d2, e + 4)  PSTEP(d3, e + 6)
        PSTEP(d4, e + 8)  PSTEP(d5, e + 10) PSTEP(d6, e + 12) PSTEP(d7, e + 14)
        e += 16;
    }
    for (; e + 2 <= eEnd; e += 2) {                 // tail pairs
        while (e == nb) EMIT(0);
        int sa = rfl(ssrc[e]), sb = rfl(ssrc[e + 1]);
        int s = h ? sb : sa;
        float2 f = __half22float2(hp[s * 32 + q]);
        vx = f.x; vy = f.y; ax += f.x; ay += f.y;
        while (e + 1 == nb) EMIT(1);
    }
    if (e < eEnd) {                                 // final single edge (half0 only)
        while (e == nb) EMIT(0);
        int sa = rfl(ssrc[e]);
        float2 f = __half22float2(hp[sa * 32 + q]);
        if (h) { f.x = 0.f; f.y = 0.f; }
        ax += f.x; ay += f.y;
        e++;
    }
    while (segi < 16) EMIT(0);                      // drain (no subtraction needed)
#undef PSTEP
#undef EMIT

    __syncthreads();                                // waves share the A tile now

    // ---- MFMA transform: wave wv -> output cols [16wv, 16wv+16), 16 nodes ----
    int rp = lane & 15;
    int g  = lane >> 4;
    const __half* ha = hin16 + (size_t)(nblk + rp) * Hd + 8 * g;
    const __half* ba = wt + (size_t)(wv * 16 + rp) * 320 + 8 * g;
    const __half* aa = alds + rp * 296 + 8 * g;
    f32x4 dacc = {0.f, 0.f, 0.f, 0.f};
    #pragma unroll
    for (int s = 0; s < 10; s++) {                  // k0 = 32*s; a-source matches (32s)
        f16x8 bfrag = *(const f16x8*)(ba + s * 32);
        f16x8 afrag;
        if (s < 2) afrag = *(const f16x8*)(ha + s * 32);
        else       afrag = *(const f16x8*)(aa + ((s - 2) >> 1) * 72 + ((s - 2) & 1) * 32);
        dacc = __builtin_amdgcn_mfma_f32_16x16x32_f16(afrag, bfrag, dacc, 0, 0, 0);
    }
    int c = wv * 16 + rp;
    float bb = bias[c];
    #pragma unroll
    for (int j = 0; j < 4; j++) {
        int row = nblk + g * 4 + j;
        float v = reluf(dacc[j] + bb);
        hout16[(size_t)row * Hd + c] = __float2half(v);
    }
}

// ---- FUSED MFConv layer: depth-4 interleaved gather -> LDS -> MFMA ----
// 4 streams x 4 rounds per iteration = 16 UNCONDITIONAL row loads in flight
// (matches rgcn's MLP). Indices via per-lane scalar loads (1 VGPR/stream-round,
// 16-lane broadcast). Length-uniform tiles -> masks fire only in last rounds.
__global__ __launch_bounds__(256) void k_mf_fused(
        const __half* __restrict__ hin16,
        const int* __restrict__ off, const int* __restrict__ ssrc,
        const int* __restrict__ order, const __half* __restrict__ mfwt,
        const float* __restrict__ bl,
        float* __restrict__ hout, __half* __restrict__ hout16, int relu_out) {
    __shared__ __align__(16) __half alds[16 * 72];  // 2.25 KB: [slot][k], stride 72
    int tid = threadIdx.x;
    int wv = tid >> 6, lane = tid & 63;
    int g2 = lane >> 4, q4 = lane & 15;
    int blk = rfl(blockIdx.x * 16);
    int ent0 = rfl(order[blk]);
    if (ent0 < 0) return;                           // entire block is pad
    int d = min(ent0 >> 20, MAXD);                  // weight index from bucket key
    const uint2* hp2 = (const uint2*)hin16;         // row = 16 uint2 (8B = 4 halves)

    int entA = rfl(order[blk + wv * 4 + 0]);
    int entB = rfl(order[blk + wv * 4 + 1]);
    int entC = rfl(order[blk + wv * 4 + 2]);
    int entD = rfl(order[blk + wv * 4 + 3]);
    int nA = (entA >= 0) ? (entA & 0xFFFFF) : 0;
    int nB = (entB >= 0) ? (entB & 0xFFFFF) : 0;
    int nC = (entC >= 0) ? (entC & 0xFFFFF) : 0;
    int nD = (entD >= 0) ? (entD & 0xFFFFF) : 0;
    int eA = rfl(off[nA * Rr]);
    int eB = rfl(off[nB * Rr]);
    int eC = rfl(off[nC * Rr]);
    int eD = rfl(off[nD * Rr]);
    int lenA = (entA >= 0) ? rfl(off[nA * Rr + Rr]) - eA : 0;
    int lenB = (entB >= 0) ? rfl(off[nB * Rr + Rr]) - eB : 0;
    int lenC = (entC >= 0) ? rfl(off[nC * Rr + Rr]) - eC : 0;
    int lenD = (entD >= 0) ? rfl(off[nD * Rr + Rr]) - eD : 0;
    int rounds = (max(max(lenA, lenB), max(lenC, lenD)) + 3) >> 2;

    float4 accA = {0.f, 0.f, 0.f, 0.f}, accB = {0.f, 0.f, 0.f, 0.f};
    float4 accC = {0.f, 0.f, 0.f, 0.f}, accD = {0.f, 0.f, 0.f, 0.f};

#define ACCM(dw, BASE, LEN, P) {                                        \
        float m_ = ((BASE) < (LEN)) ? 1.f : 0.f;                        \
        float2 f_ = __half22float2(*(__half2*)&(dw).x);                 \
        float2 h_ = __half22float2(*(__half2*)&(dw).y);                 \
        P.x = fmaf(m_, f_.x, P.x); P.y = fmaf(m_, f_.y, P.y);           \
        P.z = fmaf(m_, h_.x, P.z); P.w = fmaf(m_, h_.y, P.w); }

    // indices for rounds 0..3 (per-lane scalar: lane-group g2 reads its own slot)
    int i0A = ssrc[eA + g2],      i0B = ssrc[eB + g2];
    int i0C = ssrc[eC + g2],      i0D = ssrc[eD + g2];
    int i1A = ssrc[eA + 4 + g2],  i1B = ssrc[eB + 4 + g2];
    int i1C = ssrc[eC + 4 + g2],  i1D = ssrc[eD + 4 + g2];
    int i2A = ssrc[eA + 8 + g2],  i2B = ssrc[eB + 8 + g2];
    int i2C = ssrc[eC + 8 + g2],  i2D = ssrc[eD + 8 + g2];
    int i3A = ssrc[eA + 12 + g2], i3B = ssrc[eB + 12 + g2];
    int i3C = ssrc[eC + 12 + g2], i3D = ssrc[eD + 12 + g2];
    for (int r = 0; r < rounds; r += 4) {
        uint2 d0A = hp2[(size_t)i0A * 16 + q4];     // 16 row loads in flight
        uint2 d0B = hp2[(size_t)i0B * 16 + q4];
        uint2 d0C = hp2[(size_t)i0C * 16 + q4];
        uint2 d0D = hp2[(size_t)i0D * 16 + q4];
        uint2 d1A = hp2[(size_t)i1A * 16 + q4];
        uint2 d1B = hp2[(size_t)i1B * 16 + q4];
        uint2 d1C = hp2[(size_t)i1C * 16 + q4];
        uint2 d1D = hp2[(size_t)i1D * 16 + q4];
        uint2 d2A = hp2[(size_t)i2A * 16 + q4];
        uint2 d2B = hp2[(size_t)i2B * 16 + q4];
        uint2 d2C = hp2[(size_t)i2C * 16 + q4];
        uint2 d2D = hp2[(size_t)i2D * 16 + q4];
        uint2 d3A = hp2[(size_t)i3A * 16 + q4];
        uint2 d3B = hp2[(size_t)i3B * 16 + q4];
        uint2 d3C = hp2[(size_t)i3C * 16 + q4];
        uint2 d3D = hp2[(size_t)i3D * 16 + q4];
        int nx = 4 * (r + 4) + g2;                  // prefetch rounds r+4..r+7
        int p0A = ssrc[eA + nx],      p0B = ssrc[eB + nx];
        int p0C = ssrc[eC + nx],      p0D = ssrc[eD + nx];
        int p1A = ssrc[eA + nx + 4],  p1B = ssrc[eB + nx + 4];
        int p1C = ssrc[eC + nx + 4],  p1D = ssrc[eD + nx + 4];
        int p2A = ssrc[eA + nx + 8],  p2B = ssrc[eB + nx + 8];
        int p2C = ssrc[eC + nx + 8],  p2D = ssrc[eD + nx + 8];
        int p3A = ssrc[eA + nx + 12], p3B = ssrc[eB + nx + 12];
        int p3C = ssrc[eC + nx + 12], p3D = ssrc[eD + nx + 12];
        int b0 = 4 * r + g2, b1 = b0 + 4, b2 = b0 + 8, b3 = b0 + 12;
        ACCM(d0A, b0, lenA, accA) ACCM(d0B, b0, lenB, accB)
        ACCM(d0C, b0, lenC, accC) ACCM(d0D, b0, lenD, accD)
        ACCM(d1A, b1, lenA, accA) ACCM(d1B, b1, lenB, accB)
        ACCM(d1C, b1, lenC, accC) ACCM(d1D, b1, lenD, accD)
        ACCM(d2A, b2, lenA, accA) ACCM(d2B, b2, lenB, accB)
        ACCM(d2C, b2, lenC, accC) ACCM(d2D, b2, lenD, accD)
        ACCM(d3A, b3, lenA, accA) ACCM(d3B, b3, lenB, accB)
        ACCM(d3C, b3, lenC, accC) ACCM(d3D, b3, lenD, accD)
        i0A = p0A; i0B = p0B; i0C = p0C; i0D = p0D;
        i1A = p1A; i1B = p1B; i1C = p1C; i1D = p1D;
        i2A = p2A; i2B = p2B; i2C = p2C; i2D = p2D;
        i3A = p3A; i3B = p3B; i3C = p3C; i3D = p3D;
    }
#undef ACCM

#define REDW(P, i) {                                                    \
        P.x += __shfl_xor(P.x, 16); P.x += __shfl_xor(P.x, 32);         \
        P.y += __shfl_xor(P.y, 16); P.y += __shfl_xor(P.y, 32);         \
        P.z += __shfl_xor(P.z, 16); P.z += __shfl_xor(P.z, 32);         \
        P.w += __shfl_xor(P.w, 16); P.w += __shfl_xor(P.w, 32);         \
        if (lane < 16) {                                                \
            __half2* dst = (__half2*)&alds[(wv * 4 + (i)) * 72 + 4 * q4]; \
            dst[0] = __floats2half2_rn(P.x, P.y);                       \
            dst[1] = __floats2half2_rn(P.z, P.w); } }
    REDW(accA, 0) REDW(accB, 1) REDW(accC, 2) REDW(accD, 3)
#undef REDW
    __syncthreads();

    // ---- MFMA: wave wv -> output cols [16wv,16wv+16), rows = 16 tile slots ----
    int rp = lane & 15;
    int g  = lane >> 4;
    int entr = order[blk + rp];                     // per-lane row entry (L2-hot)
    int nr = (entr >= 0) ? (entr & 0xFFFFF) : 0;
    const __half* aa = alds + rp * 72 + 8 * g;
    const __half* ha = hin16 + (size_t)nr * Hd + 8 * g;
    const __half* ba = mfwt + ((size_t)d * Hd + wv * 16 + rp) * 128 + 8 * g;
    f32x4 dacc = {0.f, 0.f, 0.f, 0.f};
    #pragma unroll
    for (int s = 0; s < 4; s++) {                   // K=128: k<64 agg@Wl, k>=64 h@Wr
        f16x8 bfrag = *(const f16x8*)(ba + s * 32);
        f16x8 afrag = (s < 2) ? *(const f16x8*)(aa + s * 32)
                              : *(const f16x8*)(ha + (s - 2) * 32);
        dacc = __builtin_amdgcn_mfma_f32_16x16x32_f16(afrag, bfrag, dacc, 0, 0, 0);
    }
    int c = wv * 16 + rp;
    float bb = bl[d * Hd + c];
    #pragma unroll
    for (int j = 0; j < 4; j++) {
        int entw = order[blk + g * 4 + j];
        if (entw >= 0) {
            int n = entw & 0xFFFFF;
            float v = dacc[j] + bb;
            if (relu_out) hout16[(size_t)n * Hd + c] = __float2half(reluf(v));
            else          hout[(size_t)n * Hd + c] = v;   // pool path (layer 1)
        }
    }
}

// ---- global add pool (batch_idx is sorted -> mostly single fused atomic) ----
__global__ void k_pool(const float* __restrict__ h, const int* __restrict__ batch,
                       float* __restrict__ g) {
    int wave = rfl((blockIdx.x * 256 + threadIdx.x) >> 6);
    int lane = threadIdx.x & 63;
    int n0 = wave * 4;
    if (n0 >= Nn) return;
    int b0 = batch[n0], b1 = batch[n0 + 1], b2 = batch[n0 + 2], b3 = batch[n0 + 3];
    float v0 = h[(size_t)n0 * Hd + lane];
    float v1 = h[(size_t)(n0 + 1) * Hd + lane];
    float v2 = h[(size_t)(n0 + 2) * Hd + lane];
    float v3 = h[(size_t)(n0 + 3) * Hd + lane];
    if (b0 == b1 && b0 == b2 && b0 == b3) {
        unsafeAtomicAdd(&g[(size_t)b0 * Hd + lane], v0 + v1 + v2 + v3);
    } else {
        unsafeAtomicAdd(&g[(size_t)b0 * Hd + lane], v0);
        unsafeAtomicAdd(&g[(size_t)b1 * Hd + lane], v1);
        unsafeAtomicAdd(&g[(size_t)b2 * Hd + lane], v2);
        unsafeAtomicAdd(&g[(size_t)b3 * Hd + lane], v3);
    }
}

// ---- head: relu(g@lin1+b1)@lin2+b2, one wave per graph ----
__global__ void k_head(const float* __restrict__ g, const float* __restrict__ w1,
                       const float* __restrict__ b1, const float* __restrict__ w2,
                       const float* __restrict__ b2, float* __restrict__ out) {
    __shared__ float t[4][Hd];
    int wv = threadIdx.x >> 6;
    int lane = threadIdx.x & 63;
    int gi = blockIdx.x * 4 + wv;
    float acc = b1[lane];
    for (int k = 0; k < Hd; k++) acc += g[(size_t)gi * Hd + k] * w1[k * Hd + lane];
    t[wv][lane] = reluf(acc);
    __syncthreads();
    if (lane < Od) {
        float o = b2[lane];
        for (int k = 0; k < Hd; k++) o += t[wv][k] * w2[k * Od + lane];
        out[(size_t)gi * Od + lane] = o;
    }
}

extern "C" void kernel_launch(void* const* d_in, const int* in_sizes, int n_in,
                              void* d_out, int out_size, void* d_ws, size_t ws_size,
                              hipStream_t stream) {
    const float* x      = (const float*)d_in[0];
    const float* ea     = (const float*)d_in[1];
    const int*   eidx   = (const int*)d_in[2];
    const int*   batch  = (const int*)d_in[3];
    const float* emb    = (const float*)d_in[4];
    const float* lin1_w = (const float*)d_in[5];
    const float* lin1_b = (const float*)d_in[6];
    const float* lin2_w = (const float*)d_in[7];
    const float* lin2_b = (const float*)d_in[8];
    const float* rgcn_w[2]    = {(const float*)d_in[9],  (const float*)d_in[15]};
    const float* rgcn_root[2] = {(const float*)d_in[10], (const float*)d_in[16]};
    const float* rgcn_b[2]    = {(const float*)d_in[11], (const float*)d_in[17]};
    const float* mf_wl[2]     = {(const float*)d_in[12], (const float*)d_in[18]};
    const float* mf_bl[2]     = {(const float*)d_in[13], (const float*)d_in[19]};
    const float* mf_wr[2]     = {(const float*)d_in[14], (const float*)d_in[20]};

    char* p = (char*)d_ws;
    float* h32   = (float*)p; p += sizeof(float) * (size_t)Nn * Hd;
    __half* h16a = (__half*)p; p += sizeof(__half) * (size_t)Nn * Hd;
    __half* h16b = (__half*)p; p += sizeof(__half) * (size_t)Nn * Hd;
    float* gbuf  = (float*)p; p += sizeof(float) * (size_t)Ng * Hd;
    __half* wt16 = (__half*)p; p += sizeof(__half) * (size_t)2 * WT_PER_LAYER;
    __half* mfwt16 = (__half*)p; p += sizeof(__half) * (size_t)2 * MFWT_PER_LAYER;
    int* segrank = (int*)p;   p += sizeof(int) * (size_t)Ne;
    int* ssrc    = (int*)p;   p += sizeof(int) * (size_t)Ne;
    int* cnt     = (int*)p;   p += sizeof(int) * (size_t)NSEG;  // contiguous with bcnt/bfill
    int* bcnt    = (int*)p;   p += sizeof(int) * NBKT;
    int* bfill   = (int*)p;   p += sizeof(int) * NBKT;
    int* off     = (int*)p;   p += sizeof(int) * (size_t)(NSEG + 1);
    int* bsum    = (int*)p;   p += sizeof(int) * 1024;
    int* bbase   = (int*)p;   p += sizeof(int) * NBKT;
    int* order   = (int*)p;   p += sizeof(int) * (size_t)ORDER_SZ;

    hipMemsetAsync(cnt, 0, sizeof(int) * ((size_t)NSEG + 2 * NBKT), stream);
    hipMemsetAsync(gbuf, 0, sizeof(float) * (size_t)Ng * Hd, stream);

    k_rel_emb<<<NB_RELSEG + NB_EMBED + NB_PREP, 256, 0, stream>>>(
        (const float4*)ea, eidx, segrank, cnt, x, emb, h16a,
        rgcn_w[0], rgcn_root[0], rgcn_w[1], rgcn_root[1],
        mf_wl[0], mf_wr[0], mf_wl[1], mf_wr[1], wt16, mfwt16);
    k_scan1<<<SCAN_BLK, 256, 0, stream>>>(cnt, off, bsum, bcnt);
    k_scan2<<<1, 1024, 0, stream>>>(bsum, bcnt, bbase, order);
    k_scan3_bucket<<<SCAN_BLK, 256, 0, stream>>>(off, bsum, (const int4*)cnt, bbase,
                                                 bfill, order);
    k_scatter<<<Ne / 256, 256, 0, stream>>>(eidx, segrank, off, ssrc);

    __half* hin16 = h16a;  __half* hout16 = h16b;
    for (int b = 0; b < 2; b++) {
        k_rgcn_fused<<<NB_RG, 256, 0, stream>>>(hin16, off, ssrc, wt16 + b * WT_PER_LAYER,
                                                rgcn_b[b], hout16);
        k_mf_fused<<<NB_MF, 256, 0, stream>>>(hout16, off, ssrc, order,
                                              mfwt16 + b * MFWT_PER_LAYER, mf_bl[b],
                                              h32, hin16, b == 0 ? 1 : 0);
        // b=0: fp16 shadow into hin16 (next layer); b=1: fp32 into h32 (pool)
    }
    k_pool<<<Nn / 16, 256, 0, stream>>>(h32, batch, gbuf);
    k_head<<<Ng / 4, 256, 0, stream>>>(gbuf, lin1_w, lin1_b, lin2_w, lin2_b, (float*)d_out);
}

// Round 18
// 316.599 us; speedup vs baseline: 1.0619x; 1.0619x over previous
//
#include <hip/hip_runtime.h>
#include <hip/hip_fp16.h>
#include <cstdint>
#include <cstddef>

#define Nn 50000
#define Ne 800000
#define Ng 1024
#define NFd 32
#define Rr 4
#define Hd 64
#define Od 16
#define MAXD 10
#define NSEG (Nn * Rr)
#define SCAN_BLK ((NSEG + 255) / 256)
#define ORDER_SZ (Nn + 176)                // buckets padded to x16 (11*15=165 max pad); /16 exact
#define NB_MF (ORDER_SZ / 16)              // block = 16 slots (degree-uniform), 4 waves
#define NB_RG (Nn / 16)                    // block = 4 waves; 16 nodes/block (MFMA tile)
#define NB_RELSEG (Ne / 256)               // 3125 edge blocks
#define NB_EMBED (Nn / 8)                  // 6250 embed blocks (2 nodes/wave)
#define WT_PER_LAYER (Hd * 5 * Hd)         // 20480 halves: [64 cols][320 k]
#define MFWT_PER_LAYER ((MAXD + 1) * Hd * 2 * Hd)  // 90112 halves: [d][64 cols][128 k]
#define PREP_TOTAL (2 * WT_PER_LAYER + 2 * MFWT_PER_LAYER)
#define NB_PREP ((PREP_TOTAL + 255) / 256) // 864 blocks, folded into k_rel_emb grid

typedef _Float16 f16x8 __attribute__((ext_vector_type(8)));
typedef float f32x4 __attribute__((ext_vector_type(4)));

__device__ __forceinline__ float reluf(float v) { return v > 0.f ? v : 0.f; }
__device__ __forceinline__ int rfl(int v) { return __builtin_amdgcn_readfirstlane(v); }

// ---- FUSED: per-edge relation argmax/rank + embedding lookup + weight prep ----
// seg+rank packed into ONE int: (s << 12) | rank.
__global__ void k_rel_emb(const float4* __restrict__ ea, const int* __restrict__ eidx,
                          int* __restrict__ segrank,
                          int* __restrict__ cnt,
                          const float* __restrict__ x, const float* __restrict__ emb,
                          __half* __restrict__ h16,
                          const float* __restrict__ w0, const float* __restrict__ r0,
                          const float* __restrict__ w1, const float* __restrict__ r1,
                          const float* __restrict__ wl0, const float* __restrict__ wr0,
                          const float* __restrict__ wl1, const float* __restrict__ wr1,
                          __half* __restrict__ wt, __half* __restrict__ mfwt) {
    if (blockIdx.x < NB_RELSEG) {
        int e = blockIdx.x * 256 + threadIdx.x;     // exactly e < Ne
        float4 a = ea[e];
        int bi = 0; float bv = a.x;
        if (a.y > bv) { bv = a.y; bi = 1; }
        if (a.z > bv) { bv = a.z; bi = 2; }
        if (a.w > bv) { bv = a.w; bi = 3; }
        int s = eidx[Ne + e] * Rr + bi;
        int rk = atomicAdd(&cnt[s], 1);
        segrank[e] = (s << 12) | rk;
    } else if (blockIdx.x < NB_RELSEG + NB_EMBED) {
        int wave = ((blockIdx.x - NB_RELSEG) * 256 + threadIdx.x) >> 6;  // < Nn/2
        int lane = threadIdx.x & 63;
        int h = lane >> 5, q = lane & 31;
        int node = wave * 2 + h;
        float v = x[(size_t)node * NFd + q];
        int idx = q;
        #pragma unroll
        for (int o = 16; o >= 1; o >>= 1) {         // xor-butterfly within half-wave
            float ov = __shfl_xor(v, o);
            int oi = __shfl_xor(idx, o);
            if (ov > v || (ov == v && oi < idx)) { v = ov; idx = oi; }
        }
        const float2* e2 = (const float2*)(emb + (size_t)idx * Hd);
        float2 ev = e2[q];
        ((__half2*)h16)[(size_t)node * 32 + q] =
            __floats2half2_rn(reluf(ev.x), reluf(ev.y));
    } else {
        // weight prep:
        // wt  [layer][c][320]:  k<64 -> Wroot[k][c]; k=64+64r+kk -> W[r][kk][c]
        // mfwt[layer][d][c][128]: k<64 -> Wl[d][k][c]; k>=64 -> Wr[d][k-64][c]
        int idx = (blockIdx.x - NB_RELSEG - NB_EMBED) * 256 + threadIdx.x;
        if (idx < 2 * WT_PER_LAYER) {
            int b = idx / WT_PER_LAYER;
            int rem = idx % WT_PER_LAYER;
            int c = rem / 320;
            int k = rem % 320;
            const float* W  = b ? w1 : w0;
            const float* Rt = b ? r1 : r0;
            float v = (k < 64) ? Rt[k * Hd + c]
                               : W[((size_t)((k - 64) >> 6)) * Hd * Hd + ((k - 64) & 63) * Hd + c];
            wt[idx] = __float2half(v);
        } else if (idx < PREP_TOTAL) {
            int j = idx - 2 * WT_PER_LAYER;
            int b = j / MFWT_PER_LAYER;
            int rem = j % MFWT_PER_LAYER;
            int d = rem / (Hd * 128);
            int r2 = rem % (Hd * 128);
            int c = r2 / 128;
            int k = r2 % 128;
            const float* Wl = b ? wl1 : wl0;
            const float* Wr = b ? wr1 : wr0;
            float v = (k < 64) ? Wl[(size_t)d * Hd * Hd + k * Hd + c]
                               : Wr[(size_t)d * Hd * Hd + (k - 64) * Hd + c];
            mfwt[j] = __float2half(v);
        }
    }
}

// ---- scan level 1 + fused degree histogram ----
__global__ void k_scan1(const int* __restrict__ cnt, int* __restrict__ off,
                        int* __restrict__ bsum, int* __restrict__ bcnt) {
    __shared__ int s[256];
    __shared__ int hist[16];
    int t = threadIdx.x;
    if (t < 16) hist[t] = 0;
    int idx = blockIdx.x * 256 + t;
    int v = (idx < NSEG) ? cnt[idx] : 0;
    s[t] = v;
    __syncthreads();
    if ((t & 3) == 0 && idx < NSEG) {
        int dsum = s[t] + s[t + 1] + s[t + 2] + s[t + 3];
        atomicAdd(&hist[min(dsum, MAXD)], 1);
    }
    #pragma unroll
    for (int o = 1; o < 256; o <<= 1) {
        int x = (t >= o) ? s[t - o] : 0;
        __syncthreads();
        s[t] += x;
        __syncthreads();
    }
    if (idx < NSEG) off[idx] = s[t] - v;            // exclusive
    if (t == 255) bsum[blockIdx.x] = s[255];
    if (t < 16) {
        int h = hist[t];
        if (h > 0) atomicAdd(&bcnt[t], h);
    }
}

// ---- scan level 2 + fused bucket prefix (16-aligned) + order pad-slot writes ----
__global__ void k_scan2(int* __restrict__ bsum, const int* __restrict__ bcnt,
                        int* __restrict__ bbase, int* __restrict__ order) {
    __shared__ int s[1024];
    int t = threadIdx.x;
    int v = (t < SCAN_BLK) ? bsum[t] : 0;
    s[t] = v;
    __syncthreads();
    #pragma unroll
    for (int o = 1; o < 1024; o <<= 1) {
        int x = (t >= o) ? s[t - o] : 0;
        __syncthreads();
        s[t] += x;
        __syncthreads();
    }
    if (t < SCAN_BLK) bsum[t] = s[t] - v;           // exclusive block bases
    if (t == 0) {
        int run = 0;
        for (int d = 0; d <= MAXD; d++) {
            int c = bcnt[d];
            bbase[d] = run;
            int pad = (c + 15) & ~15;               // x16: MFMA tile = degree-uniform
            for (int i = c; i < pad; i++) order[run + i] = -1;
            run += pad;
        }
        for (int i = run; i < ORDER_SZ; i++) order[i] = -1;
    }
}

// ---- FUSED: scan level 3 (final off)  +  degree-bucket scatter ----
__global__ void k_scan3_bucket(int* __restrict__ off, const int* __restrict__ bsum,
                               const int4* __restrict__ cnt4, const int* __restrict__ bbase,
                               int* __restrict__ bfill, int* __restrict__ order) {
    __shared__ int hist[16];
    __shared__ int base[16];
    int t = threadIdx.x;
    if (t < 16) hist[t] = 0;
    __syncthreads();
    int idx = blockIdx.x * 256 + t;
    if (idx == 0) off[NSEG] = Ne;
    if (idx < NSEG) off[idx] = off[idx] + bsum[blockIdx.x];
    int d = 0, rk = 0;
    bool valid = (idx < Nn);
    if (valid) {
        int4 c = cnt4[idx];
        d = min(c.x + c.y + c.z + c.w, MAXD);
        rk = atomicAdd(&hist[d], 1);
    }
    __syncthreads();
    if (t < 16) {
        int h = hist[t];
        base[t] = (h > 0) ? atomicAdd(&bfill[t], h) : 0;
    }
    __syncthreads();
    if (valid) order[bbase[d] + base[d] + rk] = idx | (d << 20);
}

// ---- scatter edges into segment-sorted order: NO atomics (packed seg+rank) ----
__global__ void k_scatter(const int* __restrict__ eidx, const int* __restrict__ segrank,
                          const int* __restrict__ off, int* __restrict__ sorted_src) {
    int e = blockIdx.x * 256 + threadIdx.x;
    if (e >= Ne) return;
    int sr = segrank[e];
    int pos = off[sr >> 12] + (sr & 0xFFF);
    sorted_src[pos] = eidx[e];
}

// ---- FUSED RGCN layer: paired-edge fp16 gather, 32-edge chunks -> MFMA ----
// Half-wave h processes edge t+h of each pair; lane q=lane&31 holds cols {2q,2q+1}.
// 16 row-loads + 8 prefetched idx-loads in flight per chunk (straight-line body).
__global__ __launch_bounds__(256) void k_rgcn_fused(
        const __half* __restrict__ hin16,
        const int* __restrict__ off, const int* __restrict__ ssrc,
        const __half* __restrict__ wt, const float* __restrict__ bias,
        __half* __restrict__ hout16) {
    __shared__ __align__(16) __half alds[16 * 296];  // [node]: rel*72 + k; node stride 296
    int tid = threadIdx.x;
    int wv = tid >> 6, lane = tid & 63;
    int h = lane >> 5, q = lane & 31;
    int nblk = rfl(blockIdx.x * 16);
    int n0 = nblk + wv * 4;
    int obv = off[4 * n0 + min(lane, 16)];          // boundaries live in lanes
    int cntv = __shfl(obv, lane + 1) - obv;
    float ivv = (cntv > 0) ? 1.f / (float)cntv : 0.f;
    int e    = rfl(__shfl(obv, 0));
    int eEnd = rfl(__shfl(obv, 16));
    const __half2* hp = (const __half2*)hin16;      // row = 32 half2

    float ax = 0.f, ay = 0.f;                       // running prefix (per half)
    float px = 0.f, py = 0.f;                       // snapshot
    float vx = 0.f, vy = 0.f;                       // half's most recent added value
    int segi = 0;
    int nb = rfl(__shfl(obv, 1));

#define EMIT(SUB) do {                                               \
        float dx = ax - px, dy = ay - py;                            \
        float ox = ((SUB) && h) ? vx : 0.f;                          \
        float oy = ((SUB) && h) ? vy : 0.f;                          \
        dx -= ox; dy -= oy;                                          \
        dx += __shfl_xor(dx, 32); dy += __shfl_xor(dy, 32);          \
        float iv_ = __shfl(ivv, segi);                               \
        if (lane < 32)                                               \
            *(__half2*)&alds[(wv * 4 + (segi >> 2)) * 296            \
                             + (segi & 3) * 72 + 2 * q]              \
                = __floats2half2_rn(dx * iv_, dy * iv_);             \
        px = ax - ox; py = ay - oy;                                  \
        segi++;                                                      \
        nb = (segi < 16) ? rfl(__shfl(obv, segi + 1)) : 0x7fffffff;  \
    } while (0)

#define PSTEP(dj, t0) {                                              \
        while ((t0) == nb) EMIT(0);                                  \
        float2 f_ = __half22float2(dj);                              \
        vx = f_.x; vy = f_.y; ax += f_.x; ay += f_.y;                \
        while ((t0) + 1 == nb) EMIT(1); }

    if (e + 32 <= eEnd) {                           // 32-edge chunks, deep pipeline
        int4 iA = *(const int4*)(ssrc + e);
        int4 iB = *(const int4*)(ssrc + e + 4);
        int4 iC = *(const int4*)(ssrc + e + 8);
        int4 iD = *(const int4*)(ssrc + e + 12);
        int4 iE = *(const int4*)(ssrc + e + 16);
        int4 iF = *(const int4*)(ssrc + e + 20);
        int4 iG = *(const int4*)(ssrc + e + 24);
        int4 iH = *(const int4*)(ssrc + e + 28);
        while (true) {
            int s0 = h ? iA.y : iA.x;               // pair j: edges e+2j, e+2j+1
            int s1 = h ? iA.w : iA.z;
            int s2 = h ? iB.y : iB.x;
            int s3 = h ? iB.w : iB.z;
            int s4 = h ? iC.y : iC.x;
            int s5 = h ? iC.w : iC.z;
            int s6 = h ? iD.y : iD.x;
            int s7 = h ? iD.w : iD.z;
            int s8 = h ? iE.y : iE.x;
            int s9 = h ? iE.w : iE.z;
            int sA = h ? iF.y : iF.x;
            int sB = h ? iF.w : iF.z;
            int sC = h ? iG.y : iG.x;
            int sD = h ? iG.w : iG.z;
            int sE = h ? iH.y : iH.x;
            int sF = h ? iH.w : iH.z;
            __half2 d0 = hp[s0 * 32 + q];           // 16 paired loads in flight
            __half2 d1 = hp[s1 * 32 + q];
            __half2 d2 = hp[s2 * 32 + q];
            __half2 d3 = hp[s3 * 32 + q];
            __half2 d4 = hp[s4 * 32 + q];
            __half2 d5 = hp[s5 * 32 + q];
            __half2 d6 = hp[s6 * 32 + q];
            __half2 d7 = hp[s7 * 32 + q];
            __half2 d8 = hp[s8 * 32 + q];
            __half2 d9 = hp[s9 * 32 + q];
            __half2 dA = hp[sA * 32 + q];
            __half2 dB = hp[sB * 32 + q];
            __half2 dC = hp[sC * 32 + q];
            __half2 dD = hp[sD * 32 + q];
            __half2 dE = hp[sE * 32 + q];
            __half2 dF = hp[sF * 32 + q];
            int en = e + 32;
            bool more = (en + 32 <= eEnd);
            int4 jA, jB, jC, jD, jE, jF, jG, jH;
            if (more) {                             // prefetch next chunk's indices
                jA = *(const int4*)(ssrc + en);
                jB = *(const int4*)(ssrc + en + 4);
                jC = *(const int4*)(ssrc + en + 8);
                jD = *(const int4*)(ssrc + en + 12);
                jE = *(const int4*)(ssrc + en + 16);
                jF = *(const int4*)(ssrc + en + 20);
                jG = *(const int4*)(ssrc + en + 24);
                jH = *(const int4*)(ssrc + en + 28);
            }
            PSTEP(d0, e + 0)  PSTEP(d1, e + 2)  PSTEP(d2, e + 4)  PSTEP(d3, e + 6)
            PSTEP(d4, e + 8)  PSTEP(d5, e + 10) PSTEP(d6, e + 12) PSTEP(d7, e + 14)
            PSTEP(d8, e + 16) PSTEP(d9, e + 18) PSTEP(dA, e + 20) PSTEP(dB, e + 22)
            PSTEP(dC, e + 24) PSTEP(dD, e + 26) PSTEP(dE, e + 28) PSTEP(dF, e + 30)
            e = en;
            if (!more) break;
            iA = jA; iB = jB; iC = jC; iD = jD;
            iE = jE; iF = jF; iG = jG; iH = jH;
        }
    }
    if (e + 16 <= eEnd) {                           // tail: at most one 16-chunk
        int4 iA = *(const int4*)(ssrc + e);
        int4 iB = *(const int4*)(ssrc + e + 4);
        int4 iC = *(const int4*)(ssrc + e + 8);
        int4 iD = *(const int4*)(ssrc + e + 12);
        int s0 = h ? iA.y : iA.x;
        int s1 = h ? iA.w : iA.z;
        int s2 = h ? iB.y : iB.x;
        int s3 = h ? iB.w : iB.z;
        int s4 = h ? iC.y : iC.x;
        int s5 = h ? iC.w : iC.z;
        int s6 = h ? iD.y : iD.x;
        int s7 = h ? iD.w : iD.z;
        __half2 d0 = hp[s0 * 32 + q];
        __half2 d1 = hp[s1 * 32 + q];
        __half2 d2 = hp[s2 * 32 + q];
        __half2 d3 = hp[s3 * 32 + q];
        __half2 d4 = hp[s4 * 32 + q];
        __half2 d5 = hp[s5 * 32 + q];
        __half2 d6 = hp[s6 * 32 + q];
        __half2 d7 = hp[s7 * 32 + q];
        PSTEP(d0, e + 0)  PSTEP(d1, e + 2)  PSTEP(d2, e + 4)  PSTEP(d3, e + 6)
        PSTEP(d4, e + 8)  PSTEP(d5, e + 10) PSTEP(d6, e + 12) PSTEP(d7, e + 14)
        e += 16;
    }
    for (; e + 2 <= eEnd; e += 2) {                 // tail pairs
        while (e == nb) EMIT(0);
        int sa = rfl(ssrc[e]), sb = rfl(ssrc[e + 1]);
        int s = h ? sb : sa;
        float2 f = __half22float2(hp[s * 32 + q]);
        vx = f.x; vy = f.y; ax += f.x; ay += f.y;
        while (e + 1 == nb) EMIT(1);
    }
    if (e < eEnd) {                                 // final single edge (half0 only)
        while (e == nb) EMIT(0);
        int sa = rfl(ssrc[e]);
        float2 f = __half22float2(hp[sa * 32 + q]);
        if (h) { f.x = 0.f; f.y = 0.f; }
        ax += f.x; ay += f.y;
        e++;
    }
    while (segi < 16) EMIT(0);                      // drain (no subtraction needed)
#undef PSTEP
#undef EMIT

    __syncthreads();                                // waves share the A tile now

    // ---- MFMA transform: wave wv -> output cols [16wv, 16wv+16), 16 nodes ----
    int rp = lane & 15;
    int g  = lane >> 4;
    const __half* ha = hin16 + (size_t)(nblk + rp) * Hd + 8 * g;
    const __half* ba = wt + (size_t)(wv * 16 + rp) * 320 + 8 * g;
    const __half* aa = alds + rp * 296 + 8 * g;
    f32x4 dacc = {0.f, 0.f, 0.f, 0.f};
    #pragma unroll
    for (int s = 0; s < 10; s++) {                  // k0 = 32*s; a-source matches (32s)
        f16x8 bfrag = *(const f16x8*)(ba + s * 32);
        f16x8 afrag;
        if (s < 2) afrag = *(const f16x8*)(ha + s * 32);
        else       afrag = *(const f16x8*)(aa + ((s - 2) >> 1) * 72 + ((s - 2) & 1) * 32);
        dacc = __builtin_amdgcn_mfma_f32_16x16x32_f16(afrag, bfrag, dacc, 0, 0, 0);
    }
    int c = wv * 16 + rp;
    float bb = bias[c];
    #pragma unroll
    for (int j = 0; j < 4; j++) {
        int row = nblk + g * 4 + j;
        float v = reluf(dacc[j] + bb);
        hout16[(size_t)row * Hd + c] = __float2half(v);
    }
}

// ---- FUSED MFConv layer: masked-round interleaved gather -> LDS -> MFMA ----
// b=0 epilogue: fp16 shadow (next layer). b=1 epilogue: fp32 rows for k_pool.
__global__ __launch_bounds__(256) void k_mf_fused(
        const __half* __restrict__ hin16,
        const int* __restrict__ off, const int* __restrict__ ssrc,
        const int* __restrict__ order, const __half* __restrict__ mfwt,
        const float* __restrict__ bl,
        float* __restrict__ hout, __half* __restrict__ hout16, int relu_out) {
    __shared__ __align__(16) __half alds[16 * 72];  // 2.25 KB: [slot][k], stride 72
    int tid = threadIdx.x;
    int wv = tid >> 6, lane = tid & 63;
    int g2 = lane >> 4, q4 = lane & 15;
    int blk = rfl(blockIdx.x * 16);
    int ent0 = rfl(order[blk]);
    if (ent0 < 0) return;                           // entire block is pad
    int d = ent0 >> 20;
    const uint2* hp2 = (const uint2*)hin16;         // row = 16 uint2 (8B = 4 halves)

#define SEL4(v4) ((g2 & 2) ? ((g2 & 1) ? (v4).w : (v4).z) : ((g2 & 1) ? (v4).y : (v4).x))

    int entA = rfl(order[blk + wv * 4 + 0]);
    int entB = rfl(order[blk + wv * 4 + 1]);
    int entC = rfl(order[blk + wv * 4 + 2]);
    int entD = rfl(order[blk + wv * 4 + 3]);
    int nA = (entA >= 0) ? (entA & 0xFFFFF) : 0;
    int nB = (entB >= 0) ? (entB & 0xFFFFF) : 0;
    int nC = (entC >= 0) ? (entC & 0xFFFFF) : 0;
    int nD = (entD >= 0) ? (entD & 0xFFFFF) : 0;
    int eA = rfl(off[nA * Rr]);
    int eB = rfl(off[nB * Rr]);
    int eC = rfl(off[nC * Rr]);
    int eD = rfl(off[nD * Rr]);
    int lenA = (entA >= 0) ? rfl(off[nA * Rr + Rr]) - eA : 0;
    int lenB = (entB >= 0) ? rfl(off[nB * Rr + Rr]) - eB : 0;
    int lenC = (entC >= 0) ? rfl(off[nC * Rr + Rr]) - eC : 0;
    int lenD = (entD >= 0) ? rfl(off[nD * Rr + Rr]) - eD : 0;
    int rounds = (max(max(lenA, lenB), max(lenC, lenD)) + 3) >> 2;

    float4 accA = {0.f, 0.f, 0.f, 0.f}, accB = {0.f, 0.f, 0.f, 0.f};
    float4 accC = {0.f, 0.f, 0.f, 0.f}, accD = {0.f, 0.f, 0.f, 0.f};

    int4 ixA = *(const int4*)(ssrc + eA);           // round-0 indices (uncond, safe)
    int4 ixB = *(const int4*)(ssrc + eB);
    int4 ixC = *(const int4*)(ssrc + eC);
    int4 ixD = *(const int4*)(ssrc + eD);
    for (int r = 0; r < rounds; ++r) {
        int sA = SEL4(ixA), sB = SEL4(ixB), sC = SEL4(ixC), sD = SEL4(ixD);
        uint2 dA = hp2[(size_t)sA * 16 + q4];       // 4 row loads in flight
        uint2 dB = hp2[(size_t)sB * 16 + q4];
        uint2 dC = hp2[(size_t)sC * 16 + q4];
        uint2 dD = hp2[(size_t)sD * 16 + q4];
        int nx = 4 * (r + 1);
        int4 jxA = *(const int4*)(ssrc + eA + nx);  // uncond prefetch (masked later)
        int4 jxB = *(const int4*)(ssrc + eB + nx);
        int4 jxC = *(const int4*)(ssrc + eC + nx);
        int4 jxD = *(const int4*)(ssrc + eD + nx);
        int base = 4 * r + g2;
        float mA = (base < lenA) ? 1.f : 0.f;
        float mB = (base < lenB) ? 1.f : 0.f;
        float mC = (base < lenC) ? 1.f : 0.f;
        float mD = (base < lenD) ? 1.f : 0.f;
        float2 fA = __half22float2(*(__half2*)&dA.x);
        float2 gA = __half22float2(*(__half2*)&dA.y);
        accA.x = fmaf(mA, fA.x, accA.x); accA.y = fmaf(mA, fA.y, accA.y);
        accA.z = fmaf(mA, gA.x, accA.z); accA.w = fmaf(mA, gA.y, accA.w);
        float2 fB = __half22float2(*(__half2*)&dB.x);
        float2 gB = __half22float2(*(__half2*)&dB.y);
        accB.x = fmaf(mB, fB.x, accB.x); accB.y = fmaf(mB, fB.y, accB.y);
        accB.z = fmaf(mB, gB.x, accB.z); accB.w = fmaf(mB, gB.y, accB.w);
        float2 fC = __half22float2(*(__half2*)&dC.x);
        float2 gC = __half22float2(*(__half2*)&dC.y);
        accC.x = fmaf(mC, fC.x, accC.x); accC.y = fmaf(mC, fC.y, accC.y);
        accC.z = fmaf(mC, gC.x, accC.z); accC.w = fmaf(mC, gC.y, accC.w);
        float2 fD = __half22float2(*(__half2*)&dD.x);
        float2 gD = __half22float2(*(__half2*)&dD.y);
        accD.x = fmaf(mD, fD.x, accD.x); accD.y = fmaf(mD, fD.y, accD.y);
        accD.z = fmaf(mD, gD.x, accD.z); accD.w = fmaf(mD, gD.y, accD.w);
        ixA = jxA; ixB = jxB; ixC = jxC; ixD = jxD;
    }

#define REDW(P, i) {                                                    \
        P.x += __shfl_xor(P.x, 16); P.x += __shfl_xor(P.x, 32);         \
        P.y += __shfl_xor(P.y, 16); P.y += __shfl_xor(P.y, 32);         \
        P.z += __shfl_xor(P.z, 16); P.z += __shfl_xor(P.z, 32);         \
        P.w += __shfl_xor(P.w, 16); P.w += __shfl_xor(P.w, 32);         \
        if (lane < 16) {                                                \
            __half2* dst = (__half2*)&alds[(wv * 4 + (i)) * 72 + 4 * q4]; \
            dst[0] = __floats2half2_rn(P.x, P.y);                       \
            dst[1] = __floats2half2_rn(P.z, P.w); } }
    REDW(accA, 0) REDW(accB, 1) REDW(accC, 2) REDW(accD, 3)
#undef SEL4
#undef REDW
    __syncthreads();

    // ---- MFMA: wave wv -> output cols [16wv,16wv+16), rows = 16 tile slots ----
    int rp = lane & 15;
    int g  = lane >> 4;
    int entr = order[blk + rp];                     // per-lane row entry (L2-hot)
    int nr = (entr >= 0) ? (entr & 0xFFFFF) : 0;
    const __half* aa = alds + rp * 72 + 8 * g;
    const __half* ha = hin16 + (size_t)nr * Hd + 8 * g;
    const __half* ba = mfwt + ((size_t)d * Hd + wv * 16 + rp) * 128 + 8 * g;
    f32x4 dacc = {0.f, 0.f, 0.f, 0.f};
    #pragma unroll
    for (int s = 0; s < 4; s++) {                   // K=128: k<64 agg@Wl, k>=64 h@Wr
        f16x8 bfrag = *(const f16x8*)(ba + s * 32);
        f16x8 afrag = (s < 2) ? *(const f16x8*)(aa + s * 32)
                              : *(const f16x8*)(ha + (s - 2) * 32);
        dacc = __builtin_amdgcn_mfma_f32_16x16x32_f16(afrag, bfrag, dacc, 0, 0, 0);
    }
    int c = wv * 16 + rp;
    float bb = bl[d * Hd + c];
    #pragma unroll
    for (int j = 0; j < 4; j++) {
        int entw = order[blk + g * 4 + j];
        if (entw >= 0) {
            int n = entw & 0xFFFFF;
            float v = dacc[j] + bb;
            if (relu_out) hout16[(size_t)n * Hd + c] = __float2half(reluf(v));
            else          hout[(size_t)n * Hd + c] = v;   // pool path (layer 1)
        }
    }
}

// ---- global add pool (batch_idx is sorted -> mostly single fused atomic) ----
__global__ void k_pool(const float* __restrict__ h, const int* __restrict__ batch,
                       float* __restrict__ g) {
    int wave = rfl((blockIdx.x * 256 + threadIdx.x) >> 6);
    int lane = threadIdx.x & 63;
    int n0 = wave * 4;
    if (n0 >= Nn) return;
    int b0 = batch[n0], b1 = batch[n0 + 1], b2 = batch[n0 + 2], b3 = batch[n0 + 3];
    float v0 = h[(size_t)n0 * Hd + lane];
    float v1 = h[(size_t)(n0 + 1) * Hd + lane];
    float v2 = h[(size_t)(n0 + 2) * Hd + lane];
    float v3 = h[(size_t)(n0 + 3) * Hd + lane];
    if (b0 == b1 && b0 == b2 && b0 == b3) {
        unsafeAtomicAdd(&g[(size_t)b0 * Hd + lane], v0 + v1 + v2 + v3);
    } else {
        unsafeAtomicAdd(&g[(size_t)b0 * Hd + lane], v0);
        unsafeAtomicAdd(&g[(size_t)b1 * Hd + lane], v1);
        unsafeAtomicAdd(&g[(size_t)b2 * Hd + lane], v2);
        unsafeAtomicAdd(&g[(size_t)b3 * Hd + lane], v3);
    }
}

// ---- head: relu(g@lin1+b1)@lin2+b2, one wave per graph ----
__global__ void k_head(const float* __restrict__ g, const float* __restrict__ w1,
                       const float* __restrict__ b1, const float* __restrict__ w2,
                       const float* __restrict__ b2, float* __restrict__ out) {
    __shared__ float t[4][Hd];
    int wv = threadIdx.x >> 6;
    int lane = threadIdx.x & 63;
    int gi = blockIdx.x * 4 + wv;
    float acc = b1[lane];
    for (int k = 0; k < Hd; k++) acc += g[(size_t)gi * Hd + k] * w1[k * Hd + lane];
    t[wv][lane] = reluf(acc);
    __syncthreads();
    if (lane < Od) {
        float o = b2[lane];
        for (int k = 0; k < Hd; k++) o += t[wv][k] * w2[k * Od + lane];
        out[(size_t)gi * Od + lane] = o;
    }
}

extern "C" void kernel_launch(void* const* d_in, const int* in_sizes, int n_in,
                              void* d_out, int out_size, void* d_ws, size_t ws_size,
                              hipStream_t stream) {
    const float* x      = (const float*)d_in[0];
    const float* ea     = (const float*)d_in[1];
    const int*   eidx   = (const int*)d_in[2];
    const int*   batch  = (const int*)d_in[3];
    const float* emb    = (const float*)d_in[4];
    const float* lin1_w = (const float*)d_in[5];
    const float* lin1_b = (const float*)d_in[6];
    const float* lin2_w = (const float*)d_in[7];
    const float* lin2_b = (const float*)d_in[8];
    const float* rgcn_w[2]    = {(const float*)d_in[9],  (const float*)d_in[15]};
    const float* rgcn_root[2] = {(const float*)d_in[10], (const float*)d_in[16]};
    const float* rgcn_b[2]    = {(const float*)d_in[11], (const float*)d_in[17]};
    const float* mf_wl[2]     = {(const float*)d_in[12], (const float*)d_in[18]};
    const float* mf_bl[2]     = {(const float*)d_in[13], (const float*)d_in[19]};
    const float* mf_wr[2]     = {(const float*)d_in[14], (const float*)d_in[20]};

    char* p = (char*)d_ws;
    float* h32   = (float*)p; p += sizeof(float) * (size_t)Nn * Hd;
    __half* h16a = (__half*)p; p += sizeof(__half) * (size_t)Nn * Hd;
    __half* h16b = (__half*)p; p += sizeof(__half) * (size_t)Nn * Hd;
    float* gbuf  = (float*)p; p += sizeof(float) * (size_t)Ng * Hd;
    __half* wt16 = (__half*)p; p += sizeof(__half) * (size_t)2 * WT_PER_LAYER;
    __half* mfwt16 = (__half*)p; p += sizeof(__half) * (size_t)2 * MFWT_PER_LAYER;
    int* segrank = (int*)p;   p += sizeof(int) * (size_t)Ne;
    int* ssrc    = (int*)p;   p += sizeof(int) * (size_t)Ne;
    int* cnt     = (int*)p;   p += sizeof(int) * (size_t)NSEG;  // contiguous with bcnt/bfill
    int* bcnt    = (int*)p;   p += sizeof(int) * 16;
    int* bfill   = (int*)p;   p += sizeof(int) * 16;
    int* off     = (int*)p;   p += sizeof(int) * (size_t)(NSEG + 1);
    int* bsum    = (int*)p;   p += sizeof(int) * 1024;
    int* bbase   = (int*)p;   p += sizeof(int) * 16;
    int* order   = (int*)p;   p += sizeof(int) * (size_t)ORDER_SZ;

    hipMemsetAsync(cnt, 0, sizeof(int) * ((size_t)NSEG + 32), stream);
    hipMemsetAsync(gbuf, 0, sizeof(float) * (size_t)Ng * Hd, stream);

    k_rel_emb<<<NB_RELSEG + NB_EMBED + NB_PREP, 256, 0, stream>>>(
        (const float4*)ea, eidx, segrank, cnt, x, emb, h16a,
        rgcn_w[0], rgcn_root[0], rgcn_w[1], rgcn_root[1],
        mf_wl[0], mf_wr[0], mf_wl[1], mf_wr[1], wt16, mfwt16);
    k_scan1<<<SCAN_BLK, 256, 0, stream>>>(cnt, off, bsum, bcnt);
    k_scan2<<<1, 1024, 0, stream>>>(bsum, bcnt, bbase, order);
    k_scan3_bucket<<<SCAN_BLK, 256, 0, stream>>>(off, bsum, (const int4*)cnt, bbase,
                                                 bfill, order);
    k_scatter<<<Ne / 256, 256, 0, stream>>>(eidx, segrank, off, ssrc);

    __half* hin16 = h16a;  __half* hout16 = h16b;
    for (int b = 0; b < 2; b++) {
        k_rgcn_fused<<<NB_RG, 256, 0, stream>>>(hin16, off, ssrc, wt16 + b * WT_PER_LAYER,
                                                rgcn_b[b], hout16);
        k_mf_fused<<<NB_MF, 256, 0, stream>>>(hout16, off, ssrc, order,
                                              mfwt16 + b * MFWT_PER_LAYER, mf_bl[b],
                                              h32, hin16, b == 0 ? 1 : 0);
        // b=0: fp16 shadow into hin16 (next layer); b=1: fp32 into h32 (pool)
    }
    k_pool<<<Nn / 16, 256, 0, stream>>>(h32, batch, gbuf);
    k_head<<<Ng / 4, 256, 0, stream>>>(gbuf, lin1_w, lin1_b, lin2_w, lin2_b, (float*)d_out);
}